// Round 5
// baseline (164.475 us; speedup 1.0000x reference)
//
#include <hip/hip_runtime.h>

// Correlation layer (FlowNet-style), max_displacement=4.
// in1,in2: [8,256,128,128] fp32 -> out: [8,81,128,128] fp32
// out[b, dy*9+dx, y, x] = sum_c in1[b,c,y,x] * in2[b,c,y+dy-4,x+dx-4] (0 if OOB)
//
// Round-5: occupancy fix. Block = (batch, y-pair, x-half): 1024 blocks,
// 26.5 KB LDS -> 3 blocks x 9 waves = 27 waves/CU (was 18, grid+LDS-limited).
// Simple stage->bar->compute->bar schedule (round-4 reg-prefetch reverted:
// it cost VGPR 40->72 and halved occupancy for zero net gain).
// f16x2 channel pairs + v_dot2_f32_f16, 2 px/thread, ds_read_b64.

constexpr int Bn = 8, Cn = 256, Hn = 128, Wn = 128, HW = Hn * Wn;
constexpr int Dd = 4, ND = 9;
constexpr int KC = 16, NP = KC / 2;    // 8 f16x2 channel-pairs per chunk
constexpr int NT = 576;                // 9 waves: dy(9) x (2 rows x 32 px-pairs)
constexpr int XW = 64;                 // x-half width
constexpr int W2 = XW + 8;             // staged in2 row width (72 u32)
constexpr int NG1 = NP * 2 * (XW / 4);         // 256 in1 quad-groups
constexpr int NG2 = NP * 10 * 17;              // 1360 in2 quad-groups (16 int + 1 halo)
constexpr int NG  = NG1 + NG2;                 // 1616

typedef __fp16 h2v __attribute__((ext_vector_type(2)));

static __device__ __forceinline__ unsigned packh2(float a, float b) {
  h2v h = __builtin_amdgcn_cvt_pkrtz(a, b);   // a->low, b->high
  return __builtin_bit_cast(unsigned, h);
}

static __device__ __forceinline__ float dot2(unsigned a, unsigned b, float c) {
#if __has_builtin(__builtin_amdgcn_fdot2)
  return __builtin_amdgcn_fdot2(__builtin_bit_cast(h2v, a),
                                __builtin_bit_cast(h2v, b), c, false);
#else
  h2v ha = __builtin_bit_cast(h2v, a), hb = __builtin_bit_cast(h2v, b);
  return c + (float)ha.x * (float)hb.x + (float)ha.y * (float)hb.y;
#endif
}

__global__ __launch_bounds__(NT) void corr_kernel(
    const float* __restrict__ in1, const float* __restrict__ in2,
    float* __restrict__ out)
{
  __shared__ __align__(16) unsigned s1h[NP][2][XW];    // 4 KB
  __shared__ __align__(16) unsigned s2h[NP][10][W2];   // 22.5 KB

  // XCD-chunked swizzle: 1024 blocks, 8 XCDs, bijective (1024 % 8 == 0);
  // each XCD gets 128 consecutive blocks = exactly one batch.
  int bid = blockIdx.x;
  bid = (bid & 7) * 128 + (bid >> 3);
  const int b     = bid >> 7;
  const int yp    = (bid >> 1) & 63;
  const int xh    = bid & 1;
  const int y0    = yp << 1;
  const int xbase = xh << 6;           // 0 or 64

  const int tid  = threadIdx.x;
  const int dy   = tid >> 6;           // 0..8 (wave id)
  const int lane = tid & 63;
  const int row  = lane >> 5;          // 0..1
  const int x0   = (lane & 31) << 1;   // local px pair 0..62
  const int srow = dy + row;
  const size_t base = (size_t)b * Cn * HW;

  // ---- pre-zero the OUTER x-halo quad of each (pair,row): written only here.
  //      xh=0: cols [0,4) (gx<0); xh=1: cols [68,72) (gx>=128).
  for (int i = tid; i < NP * 10; i += NT) {
    const int p = i / 10, r = i - p * 10;
    *(uint4*)&s2h[p][r][xh ? 68 : 0] = uint4{0, 0, 0, 0};
  }

  float2 acc[ND];
#pragma unroll
  for (int dx = 0; dx < ND; ++dx) acc[dx] = float2{0.f, 0.f};

  for (int c0 = 0; c0 < Cn; c0 += KC) {
    __syncthreads();                   // prev compute done (1st iter: prezero)

    // ---- stage chunk: NG float4-groups, pack fp32 channel-pair -> f16x2 ----
    for (int i = tid; i < NG; i += NT) {
      if (i < NG1) {                   // in1: p(8) x row(2) x quad(16)
        const int p = i >> 5, yy = (i >> 4) & 1, q = i & 15;
        const float* s =
            in1 + base + (size_t)(c0 + 2 * p) * HW + (y0 + yy) * Wn + xbase + (q << 2);
        const float4 f0 = *(const float4*)s;
        const float4 f1 = *(const float4*)(s + HW);
        uint4 w;
        w.x = packh2(f0.x, f1.x); w.y = packh2(f0.y, f1.y);
        w.z = packh2(f0.z, f1.z); w.w = packh2(f0.w, f1.w);
        *(uint4*)&s1h[p][yy][q << 2] = w;
      } else {                         // in2: p(8) x row(10) x quad(17)
        int g = i - NG1;
        const int p = g / 170; g -= p * 170;
        const int r = g / 17;
        const int q = g - r * 17;
        const int gy = y0 + r - Dd;
        const bool ok = (unsigned)gy < (unsigned)Hn;
        int dstx, gx;
        if (q < 16) { dstx = 4 + (q << 2); gx = xbase + (q << 2); }
        else {       // inner-side halo quad (real data from the other x-half)
          dstx = xh ? 0 : 68;
          gx   = xh ? (xbase - 4) : (xbase + 64);
        }
        const float* s =
            in2 + base + (size_t)(c0 + 2 * p) * HW + (size_t)(ok ? gy : 0) * Wn + gx;
        const float4 f0 = *(const float4*)s;
        const float4 f1 = *(const float4*)(s + HW);
        uint4 w;
        w.x = packh2(f0.x, f1.x); w.y = packh2(f0.y, f1.y);
        w.z = packh2(f0.z, f1.z); w.w = packh2(f0.w, f1.w);
        if (!ok) w = uint4{0, 0, 0, 0};
        *(uint4*)&s2h[p][r][dstx] = w;
      }
    }
    __syncthreads();

    // ---- compute: per pair 1+5 ds_read_b64 -> 18 dot2 (36 MACs) ----
#pragma unroll
    for (int kc = 0; kc < NP; ++kc) {
      const uint2 aa = *(const uint2*)&s1h[kc][row][x0];
      const unsigned* bp = &s2h[kc][srow][x0];
      unsigned bb[10];
#pragma unroll
      for (int j = 0; j < 5; ++j)
        *(uint2*)&bb[2 * j] = *(const uint2*)(bp + 2 * j);
#pragma unroll
      for (int dx = 0; dx < ND; ++dx) {
        acc[dx].x = dot2(aa.x, bb[dx], acc[dx].x);
        acc[dx].y = dot2(aa.y, bb[dx + 1], acc[dx].y);
      }
    }
  }

  // ---- epilogue: coalesced float2 stores ----
#pragma unroll
  for (int dx = 0; dx < ND; ++dx) {
    const size_t o =
        (((size_t)b * (ND * ND) + dy * ND + dx) * Hn + (y0 + row)) * Wn + xbase + x0;
    *(float2*)&out[o] = acc[dx];
  }
}

extern "C" void kernel_launch(void* const* d_in, const int* in_sizes, int n_in,
                              void* d_out, int out_size, void* d_ws, size_t ws_size,
                              hipStream_t stream) {
  const float* in1 = (const float*)d_in[0];
  const float* in2 = (const float*)d_in[1];
  float* out = (float*)d_out;
  dim3 grid(Bn * (Hn / 2) * 2);   // 1024 blocks: (batch, y-pair, x-half)
  dim3 block(NT);                 // 576 threads = 9 waves
  hipLaunchKernelGGL(corr_kernel, grid, block, 0, stream, in1, in2, out);
}

// Round 6
// 151.245 us; speedup vs baseline: 1.0875x; 1.0875x over previous
//
#include <hip/hip_runtime.h>

// Correlation layer (FlowNet-style), max_displacement=4.
// in1,in2: [8,256,128,128] fp32 -> out: [8,81,128,128] fp32
// out[b, dy*9+dx, y, x] = sum_c in1[b,c,y,x] * in2[b,c,y+dy-4,x+dx-4] (0 if OOB)
//
// Round-6: LDS-read-pipe fix. The LDS read pipe (per-CU, 4 SIMDs share) was
// the bottleneck: r3 spent ~46us/CU on ds_read_b128 vs 17us dot2 issue.
//  - in1 no longer staged in LDS: per-thread global dwordx4 (L1/L2-served),
//    packed in-register. LDS reads drop 4->3 b128 per 72 MAC.
//  - dy split across BLOCKS (groups of 3): block = (b, y-pair, dy-group),
//    1536 blocks x 192 thr (3 waves), LDS 17.4KB -> up to 9 blocks/CU,
//    target 27 waves/CU (launch_bounds(192,7) caps VGPR at ~73).
//  - same conflict-free b128 window pattern as r3.

constexpr int Bn = 8, Cn = 256, Hn = 128, Wn = 128, HW = Hn * Wn;
constexpr int Dd = 4, ND = 9;
constexpr int KC = 16, NP = KC / 2;    // 8 f16x2 channel-pairs per chunk
constexpr int NT = 192;                // 3 waves = one dy-group
constexpr int NR = 4;                  // staged in2 rows (dy-group span + 1)
constexpr int W2 = Wn + 8;             // staged row width (136 u32)

typedef __fp16 h2v __attribute__((ext_vector_type(2)));

static __device__ __forceinline__ unsigned packh2(float a, float b) {
  h2v h = __builtin_amdgcn_cvt_pkrtz(a, b);   // a->low, b->high
  return __builtin_bit_cast(unsigned, h);
}

static __device__ __forceinline__ float dot2(unsigned a, unsigned b, float c) {
#if __has_builtin(__builtin_amdgcn_fdot2)
  return __builtin_amdgcn_fdot2(__builtin_bit_cast(h2v, a),
                                __builtin_bit_cast(h2v, b), c, false);
#else
  h2v ha = __builtin_bit_cast(h2v, a), hb = __builtin_bit_cast(h2v, b);
  return c + (float)ha.x * (float)hb.x + (float)ha.y * (float)hb.y;
#endif
}

__global__ __launch_bounds__(NT, 7) void corr_kernel(
    const float* __restrict__ in1, const float* __restrict__ in2,
    float* __restrict__ out)
{
  __shared__ __align__(16) unsigned s2h[NP][NR][W2];   // 17.4 KB (in2 only)

  // XCD-chunked swizzle: 1536 blocks, 8 XCDs, bijective (1536 % 8 == 0);
  // 192 consecutive blocks (one batch) per XCD.
  int bid = blockIdx.x;
  bid = (bid & 7) * 192 + (bid >> 3);
  const int b   = bid / 192;
  int rem = bid - b * 192;
  const int yp  = rem / 3;             // y-pair index (dyg fastest: dy-groups
  const int dyg = rem - yp * 3;        //  of same y-rows adjacent -> L2 reuse)
  const int y0  = yp << 1;

  const int tid  = threadIdx.x;
  const int wv   = tid >> 6;           // wave 0..2
  const int dy   = dyg * 3 + wv;       // 0..8
  const int lane = tid & 63;
  const int row  = lane >> 5;          // 0..1
  const int x0   = (lane & 31) << 2;   // 4 consecutive px
  const int rr   = wv + row;           // staged in2 row index 0..3
  const size_t base = (size_t)b * Cn * HW;

  // pre-zero x-halo quads (cols 0..3, 132..135): written only here.
  for (int i = tid; i < NP * NR * 2; i += NT) {
    const int p = i >> 3, r = (i >> 1) & 3, side = i & 1;
    *(uint4*)&s2h[p][r][side ? 132 : 0] = uint4{0, 0, 0, 0};
  }

  float4 acc[ND];
#pragma unroll
  for (int dx = 0; dx < ND; ++dx) acc[dx] = float4{0.f, 0.f, 0.f, 0.f};

  const float* in1p = in1 + base + (size_t)(y0 + row) * Wn + x0;

  for (int c0 = 0; c0 < Cn; c0 += KC) {
    __syncthreads();                   // prev compute done (1st: pre-zero)

    // ---- stage in2 interior: NP*NR*32 = 1024 quad-groups ----
    for (int g = tid; g < NP * NR * 32; g += NT) {
      const int p = g >> 7;
      const int r = (g >> 5) & 3;
      const int q = g & 31;
      const int gy = y0 + dyg * 3 + r - Dd;
      const bool ok = (unsigned)gy < (unsigned)Hn;
      const float* s = in2 + base + (size_t)(c0 + 2 * p) * HW +
                       (size_t)(ok ? gy : 0) * Wn + (q << 2);
      const float4 f0 = *(const float4*)s;
      const float4 f1 = *(const float4*)(s + HW);
      uint4 w;
      w.x = packh2(f0.x, f1.x); w.y = packh2(f0.y, f1.y);
      w.z = packh2(f0.z, f1.z); w.w = packh2(f0.w, f1.w);
      if (!ok) w = uint4{0, 0, 0, 0};
      *(uint4*)&s2h[p][r][(q << 2) + 4] = w;
    }
    __syncthreads();

    // ---- compute: per pair, in1 from global (2x dwordx4 + 4 pk),
    //      in2 window 3x ds_read_b128 -> 36 dot2 (72 MAC) ----
    const float* ip = in1p + (size_t)c0 * HW;
#pragma unroll
    for (int p = 0; p < NP; ++p) {
      const float4 f0 = *(const float4*)(ip + (size_t)(2 * p) * HW);
      const float4 f1 = *(const float4*)(ip + (size_t)(2 * p + 1) * HW);
      const unsigned aa[4] = {packh2(f0.x, f1.x), packh2(f0.y, f1.y),
                              packh2(f0.z, f1.z), packh2(f0.w, f1.w)};
      const unsigned* bp = &s2h[p][rr][x0];
      const uint4 b0 = *(const uint4*)bp;
      const uint4 b1 = *(const uint4*)(bp + 4);
      const uint4 b2 = *(const uint4*)(bp + 8);
      const unsigned bb[12] = {b0.x, b0.y, b0.z, b0.w, b1.x, b1.y,
                               b1.z, b1.w, b2.x, b2.y, b2.z, b2.w};
#pragma unroll
      for (int dx = 0; dx < ND; ++dx) {
        acc[dx].x = dot2(aa[0], bb[dx + 0], acc[dx].x);
        acc[dx].y = dot2(aa[1], bb[dx + 1], acc[dx].y);
        acc[dx].z = dot2(aa[2], bb[dx + 2], acc[dx].z);
        acc[dx].w = dot2(aa[3], bb[dx + 3], acc[dx].w);
      }
    }
  }

  // ---- epilogue: coalesced float4 stores ----
#pragma unroll
  for (int dx = 0; dx < ND; ++dx) {
    const size_t o =
        (((size_t)b * (ND * ND) + dy * ND + dx) * Hn + (y0 + row)) * Wn + x0;
    *(float4*)&out[o] = acc[dx];
  }
}

extern "C" void kernel_launch(void* const* d_in, const int* in_sizes, int n_in,
                              void* d_out, int out_size, void* d_ws, size_t ws_size,
                              hipStream_t stream) {
  const float* in1 = (const float*)d_in[0];
  const float* in2 = (const float*)d_in[1];
  float* out = (float*)d_out;
  dim3 grid(Bn * (Hn / 2) * 3);   // 1536 blocks: (batch, y-pair, dy-group)
  dim3 block(NT);                 // 192 threads = 3 waves
  hipLaunchKernelGGL(corr_kernel, grid, block, 0, stream, in1, in2, out);
}